// Round 5
// baseline (10916.496 us; speedup 1.0000x reference)
//
#include <hip/hip_runtime.h>
#include <math.h>

#define B_   8
#define S_   1024
#define FIN  32
#define D_   512
#define H_   8
#define L_   6
#define DFF_ 2048
#define DK_  64

// non-contracted f32 ops (emulate numpy einsum: separate mul + add, no FMA)
__device__ __forceinline__ float mulrn(float a, float b) { return __fmul_rn(a, b); }
__device__ __forceinline__ float addrn(float a, float b) { return __fadd_rn(a, b); }

// ---------------- embed: h = (x @ emb_w + emb_b) + pe  [f32, sequential-k FMA] ----------------
__global__ __launch_bounds__(128) void k_embed(const float* __restrict__ x,
                                               const float* __restrict__ emb_w,
                                               const float* __restrict__ emb_b,
                                               const float* __restrict__ pe,
                                               float* __restrict__ h) {
    int row = blockIdx.x;            // b*S + s
    int s = row & (S_ - 1);
    int t = threadIdx.x;             // 128 threads, 4 cols each
    __shared__ float xs[FIN];
    if (t < FIN) xs[t] = x[row * FIN + t];
    __syncthreads();
    int d = t * 4;
    float a0 = 0.f, a1 = 0.f, a2 = 0.f, a3 = 0.f;
#pragma unroll
    for (int k = 0; k < FIN; ++k) {          // strict k-ascending single-chain FMA (BLAS-like)
        float xv = xs[k];
        const float* wr = &emb_w[k * D_ + d];
        a0 = fmaf(xv, wr[0], a0);
        a1 = fmaf(xv, wr[1], a1);
        a2 = fmaf(xv, wr[2], a2);
        a3 = fmaf(xv, wr[3], a3);
    }
    const float* bb = &emb_b[d];
    const float* pp = &pe[s * D_ + d];
    float4 o;
    o.x = addrn(addrn(a0, bb[0]), pp[0]);    // (matmul + bias) + pe, np op order
    o.y = addrn(addrn(a1, bb[1]), pp[1]);
    o.z = addrn(addrn(a2, bb[2]), pp[2]);
    o.w = addrn(addrn(a3, bb[3]), pp[3]);
    *(float4*)&h[(size_t)row * D_ + d] = o;
}

// ---------------- tiled f32 GEMM: C = A[M,K] @ W[K,N] + bias ----------------
// Per-element: single accumulator, strict k-ascending FMA chain (matches BLAS sgemm
// micro-kernel semantics). 64x64 tile, BK=16, 256 threads, 4x4 per thread.
template<bool RELU>
__global__ __launch_bounds__(256) void k_gemm(const float* __restrict__ A,
                                              const float* __restrict__ W,
                                              const float* __restrict__ bias,
                                              float* __restrict__ C,
                                              int M, int N, int K) {
    __shared__ float As[16][68];   // [k][m]
    __shared__ float Bs[16][68];   // [k][n]
    int bm = blockIdx.y * 64, bn = blockIdx.x * 64;
    int t = threadIdx.x;
    int tr = t >> 4, tc = t & 15;          // compute map
    int ar = t >> 2, ak = (t & 3) * 4;     // A load map
    int wk = t >> 4, wn = (t & 15) * 4;    // W load map
    float acc[4][4] = {};
    for (int k0 = 0; k0 < K; k0 += 16) {   // k-panels ascending
        float4 a4 = *(const float4*)&A[(size_t)(bm + ar) * K + k0 + ak];
        float4 w4 = *(const float4*)&W[(size_t)(k0 + wk) * N + bn + wn];
        __syncthreads();
        As[ak + 0][ar] = a4.x; As[ak + 1][ar] = a4.y;
        As[ak + 2][ar] = a4.z; As[ak + 3][ar] = a4.w;
        *(float4*)&Bs[wk][wn] = w4;
        __syncthreads();
#pragma unroll
        for (int kk = 0; kk < 16; ++kk) {  // ascending within panel
            float4 av = *(const float4*)&As[kk][tr * 4];
            float4 bv = *(const float4*)&Bs[kk][tc * 4];
            acc[0][0] = fmaf(av.x, bv.x, acc[0][0]); acc[0][1] = fmaf(av.x, bv.y, acc[0][1]);
            acc[0][2] = fmaf(av.x, bv.z, acc[0][2]); acc[0][3] = fmaf(av.x, bv.w, acc[0][3]);
            acc[1][0] = fmaf(av.y, bv.x, acc[1][0]); acc[1][1] = fmaf(av.y, bv.y, acc[1][1]);
            acc[1][2] = fmaf(av.y, bv.z, acc[1][2]); acc[1][3] = fmaf(av.y, bv.w, acc[1][3]);
            acc[2][0] = fmaf(av.z, bv.x, acc[2][0]); acc[2][1] = fmaf(av.z, bv.y, acc[2][1]);
            acc[2][2] = fmaf(av.z, bv.z, acc[2][2]); acc[2][3] = fmaf(av.z, bv.w, acc[2][3]);
            acc[3][0] = fmaf(av.w, bv.x, acc[3][0]); acc[3][1] = fmaf(av.w, bv.y, acc[3][1]);
            acc[3][2] = fmaf(av.w, bv.z, acc[3][2]); acc[3][3] = fmaf(av.w, bv.w, acc[3][3]);
        }
    }
    float4 b4 = *(const float4*)&bias[bn + tc * 4];
#pragma unroll
    for (int i = 0; i < 4; ++i) {
        float4 o;
        o.x = addrn(acc[i][0], b4.x); o.y = addrn(acc[i][1], b4.y);
        o.z = addrn(acc[i][2], b4.z); o.w = addrn(acc[i][3], b4.w);
        if (RELU) {
            o.x = fmaxf(o.x, 0.f); o.y = fmaxf(o.y, 0.f);
            o.z = fmaxf(o.z, 0.f); o.w = fmaxf(o.w, 0.f);
        }
        *(float4*)&C[(size_t)(bm + tr * 4 + i) * N + bn + tc * 4] = o;
    }
}

// ---------------- attention, numpy-faithful f32 ----------------
// grid (H, S/16, B); block 256 = 16 rows x 16 lanes.
// scores: per (q,k) element strict d-ascending NON-FMA chain (np.einsum semantics), /8 at end.
// softmax: global row max (exact), p = expf(s - m), attn = p / denom (elementwise division).
// PV: per (q,d) element strict k-ascending NON-FMA chain over all 1024 keys.
// ctx aliases q safely: q read only at start, rows disjoint across blocks.
__global__ __launch_bounds__(256) void k_attn(const float* q,
                                              const float* __restrict__ kg,
                                              const float* __restrict__ vg,
                                              float* ctx) {
    __shared__ float Qs[16][72];
    __shared__ float Ks[16][72];
    __shared__ float Ss[16][1024];
    int hh = blockIdx.x;
    int ch = blockIdx.y;
    int b  = blockIdx.z;
    int t  = threadIdx.x;
    int r  = t >> 4, c16 = t & 15;
    const int row0 = ch * 16;
    const size_t base = (size_t)b * S_ * D_ + hh * DK_;

    // stage Q chunk (16x64)
    *(float4*)&Qs[t >> 4][(t & 15) * 4] =
        *(const float4*)&q[base + (size_t)(row0 + (t >> 4)) * D_ + (t & 15) * 4];
    __syncthreads();

    // phase A: scores, one (r, key) pair per thread per 16-key tile
    for (int tile = 0; tile < 64; ++tile) {
        *(float4*)&Ks[t >> 4][(t & 15) * 4] =
            *(const float4*)&kg[base + (size_t)(tile * 16 + (t >> 4)) * D_ + (t & 15) * 4];
        __syncthreads();
        float s = 0.f;
#pragma unroll
        for (int d = 0; d < 64; ++d)                     // strict d-ascending, no FMA
            s = addrn(s, mulrn(Qs[r][d], Ks[c16][d]));
        Ss[r][tile * 16 + c16] = s * 0.125f;             // / sqrt(64), exact
        __syncthreads();
    }

    // phase B: exact row max (thread's 64-slice + 16-lane tree; fmax order-exact)
    float mx = -INFINITY;
    for (int j = 0; j < 64; ++j) mx = fmaxf(mx, Ss[r][c16 * 64 + j]);
    mx = fmaxf(mx, __shfl_xor(mx, 1));
    mx = fmaxf(mx, __shfl_xor(mx, 2));
    mx = fmaxf(mx, __shfl_xor(mx, 4));
    mx = fmaxf(mx, __shfl_xor(mx, 8));

    // phase C: p = exp(s - m); denom; attn = p / denom  (elementwise f32 division)
    float psum = 0.f;
    for (int j = 0; j < 64; ++j) {
        float p = expf(__fsub_rn(Ss[r][c16 * 64 + j], mx));
        Ss[r][c16 * 64 + j] = p;
        psum = addrn(psum, p);
    }
    psum = addrn(psum, __shfl_xor(psum, 1));
    psum = addrn(psum, __shfl_xor(psum, 2));
    psum = addrn(psum, __shfl_xor(psum, 4));
    psum = addrn(psum, __shfl_xor(psum, 8));
    for (int j = 0; j < 64; ++j)
        Ss[r][c16 * 64 + j] = __fdiv_rn(Ss[r][c16 * 64 + j], psum);
    __syncthreads();

    // phase D: ctx[r][d] = sum_j attn[r][j] * v[j][d], strict j-ascending, no FMA
    int d0 = c16 * 4;
    float a0 = 0.f, a1 = 0.f, a2 = 0.f, a3 = 0.f;
    for (int j = 0; j < S_; ++j) {
        float p = Ss[r][j];
        float4 v4 = *(const float4*)&vg[base + (size_t)j * D_ + d0];
        a0 = addrn(a0, mulrn(p, v4.x));
        a1 = addrn(a1, mulrn(p, v4.y));
        a2 = addrn(a2, mulrn(p, v4.z));
        a3 = addrn(a3, mulrn(p, v4.w));
    }
    float4 o = {a0, a1, a2, a3};
    *(float4*)&ctx[base + (size_t)(row0 + r) * D_ + d0] = o;
}

// ---------------- h = LN(h + res), f32 two-pass (np expression order) ----------------
__global__ __launch_bounds__(256) void k_add_ln(float* h,
                                                const float* __restrict__ res,
                                                const float* __restrict__ g,
                                                const float* __restrict__ bta) {
    int row = blockIdx.x;
    int t = threadIdx.x;
    size_t base = (size_t)row * D_;
    float y0 = addrn(h[base + t],       res[base + t]);
    float y1 = addrn(h[base + t + 256], res[base + t + 256]);
    __shared__ float red[4];
    int w = t >> 6;
    float s = y0 + y1;
#pragma unroll
    for (int o = 1; o < 64; o <<= 1) s += __shfl_xor(s, o);
    if ((t & 63) == 0) red[w] = s;
    __syncthreads();
    float mean = (red[0] + red[1] + red[2] + red[3]) * (1.f / D_);
    __syncthreads();
    float d0 = __fsub_rn(y0, mean), d1 = __fsub_rn(y1, mean);
    s = mulrn(d0, d0) + mulrn(d1, d1);
#pragma unroll
    for (int o = 1; o < 64; o <<= 1) s += __shfl_xor(s, o);
    if ((t & 63) == 0) red[w] = s;
    __syncthreads();
    float var = (red[0] + red[1] + red[2] + red[3]) * (1.f / D_);
    float rstd = __fdiv_rn(1.0f, sqrtf(__fadd_rn(var, 1e-5f)));
    h[base + t]       = addrn(mulrn(mulrn(d0, rstd), g[t]),       bta[t]);
    h[base + t + 256] = addrn(mulrn(mulrn(d1, rstd), g[t + 256]), bta[t + 256]);
}

// ---------------- pooled = mean over S (f32) ----------------
__global__ __launch_bounds__(256) void k_pool(const float* __restrict__ h,
                                              float* __restrict__ pooled) {
    int blk = blockIdx.x;           // B*8
    int b = blk >> 3, dc = (blk & 7) * 64;
    int t = threadIdx.x;
    int d = dc + (t & 63), sg = t >> 6;
    float s = 0.f;
    for (int ss = sg; ss < S_; ss += 4)
        s = addrn(s, h[((size_t)b * S_ + ss) * D_ + d]);
    __shared__ float sh[4][64];
    sh[sg][t & 63] = s;
    __syncthreads();
    if (t < 64)
        pooled[b * D_ + dc + t] = (sh[0][t] + sh[1][t] + sh[2][t] + sh[3][t]) * (1.f / S_);
}

// ---------------- head MLP (single block, f32, sequential-k FMA) ----------------
__global__ __launch_bounds__(256) void k_head(const float* __restrict__ pooled,
                                              const float* __restrict__ w1, const float* __restrict__ b1,
                                              const float* __restrict__ w2, const float* __restrict__ b2,
                                              const float* __restrict__ w3, const float* __restrict__ b3,
                                              float* __restrict__ out) {
    __shared__ float ps[B_][D_];
    __shared__ float z1[B_][256];
    __shared__ float z2[B_][128];
    int t = threadIdx.x;
    for (int i = t; i < B_ * D_; i += 256) ps[i >> 9][i & 511] = pooled[i];
    __syncthreads();
    {
        float acc[B_] = {};
        for (int k = 0; k < D_; ++k) {
            float w = w1[k * 256 + t];
#pragma unroll
            for (int b = 0; b < B_; ++b) acc[b] = fmaf(ps[b][k], w, acc[b]);
        }
#pragma unroll
        for (int b = 0; b < B_; ++b) z1[b][t] = fmaxf(addrn(acc[b], b1[t]), 0.f);
    }
    __syncthreads();
    if (t < 128) {
        float acc[B_] = {};
        for (int k = 0; k < 256; ++k) {
            float w = w2[k * 128 + t];
#pragma unroll
            for (int b = 0; b < B_; ++b) acc[b] = fmaf(z1[b][k], w, acc[b]);
        }
#pragma unroll
        for (int b = 0; b < B_; ++b) z2[b][t] = fmaxf(addrn(acc[b], b2[t]), 0.f);
    }
    __syncthreads();
    if (t < B_ * 3) {
        int b = t / 3, c = t % 3;
        float acc = 0.f;
        for (int k = 0; k < 128; ++k) acc = fmaf(z2[b][k], w3[k * 3 + c], acc);
        out[t] = addrn(acc, b3[c]);
    }
}

extern "C" void kernel_launch(void* const* d_in, const int* in_sizes, int n_in,
                              void* d_out, int out_size, void* d_ws, size_t ws_size,
                              hipStream_t stream) {
    const float* x     = (const float*)d_in[0];
    const float* pe    = (const float*)d_in[1];
    const float* emb_w = (const float*)d_in[2];
    const float* emb_b = (const float*)d_in[3];
    const float* Wq    = (const float*)d_in[4];
    const float* bq    = (const float*)d_in[5];
    const float* Wk    = (const float*)d_in[6];
    const float* bk    = (const float*)d_in[7];
    const float* Wv    = (const float*)d_in[8];
    const float* bv    = (const float*)d_in[9];
    const float* Wo    = (const float*)d_in[10];
    const float* bo    = (const float*)d_in[11];
    const float* ln1_g = (const float*)d_in[12];
    const float* ln1_b = (const float*)d_in[13];
    const float* ln2_g = (const float*)d_in[14];
    const float* ln2_b = (const float*)d_in[15];
    const float* W1    = (const float*)d_in[16];
    const float* b1    = (const float*)d_in[17];
    const float* W2    = (const float*)d_in[18];
    const float* b2    = (const float*)d_in[19];
    const float* fc1_w = (const float*)d_in[20];
    const float* fc1_b = (const float*)d_in[21];
    const float* fc2_w = (const float*)d_in[22];
    const float* fc2_b = (const float*)d_in[23];
    const float* fc3_w = (const float*)d_in[24];
    const float* fc3_b = (const float*)d_in[25];

    const size_t NBS = (size_t)B_ * S_ * D_;   // 4,194,304 floats
    float* ws = (float*)d_ws;
    const int MROWS = B_ * S_;                 // 8192

    // layout (f32, 67.1 MB): h | q | k | v | pooled  (ctx->q, Wo-out->k, W2-out->v, ff1 over q+k)
    float* h = ws;
    float* q = h + NBS;
    float* k = q + NBS;
    float* v = k + NBS;
    float* pooled = v + NBS;

    k_embed<<<MROWS, 128, 0, stream>>>(x, emb_w, emb_b, pe, h);

    dim3 g512(D_ / 64, MROWS / 64);        // (8,128)
    dim3 gff(DFF_ / 64, 4096 / 64);        // (32,64)  per 4096-row chunk
    dim3 gw2(D_ / 64, 4096 / 64);          // (8,64)
    dim3 gattn(H_, S_ / 16, B_);           // (8,64,8)

    for (int l = 0; l < L_; ++l) {
        const float* wq = Wq + (size_t)l * D_ * D_;
        const float* wk = Wk + (size_t)l * D_ * D_;
        const float* wv = Wv + (size_t)l * D_ * D_;
        const float* wo = Wo + (size_t)l * D_ * D_;
        k_gemm<false><<<g512, 256, 0, stream>>>(h, wq, bq + l * D_, q, MROWS, D_, D_);
        k_gemm<false><<<g512, 256, 0, stream>>>(h, wk, bk + l * D_, k, MROWS, D_, D_);
        k_gemm<false><<<g512, 256, 0, stream>>>(h, wv, bv + l * D_, v, MROWS, D_, D_);
        k_attn<<<gattn, 256, 0, stream>>>(q, k, v, q);                 // ctx in place
        k_gemm<false><<<g512, 256, 0, stream>>>(q, wo, bo + l * D_, k, MROWS, D_, D_);
        k_add_ln<<<MROWS, 256, 0, stream>>>(h, k, ln1_g + l * D_, ln1_b + l * D_);
        for (int c = 0; c < 2; ++c) {
            float* ff1 = q;                                            // 4096x2048 over dead q+k
            k_gemm<true ><<<gff, 256, 0, stream>>>(h + (size_t)c * 4096 * D_,
                W1 + (size_t)l * D_ * DFF_, b1 + l * DFF_, ff1, 4096, DFF_, D_);
            k_gemm<false><<<gw2, 256, 0, stream>>>(ff1,
                W2 + (size_t)l * DFF_ * D_, b2 + l * D_, v + (size_t)c * 4096 * D_, 4096, D_, DFF_);
        }
        k_add_ln<<<MROWS, 256, 0, stream>>>(h, v, ln2_g + l * D_, ln2_b + l * D_);
    }

    k_pool<<<B_ * 8, 256, 0, stream>>>(h, pooled);
    k_head<<<1, 256, 0, stream>>>(pooled, fc1_w, fc1_b, fc2_w, fc2_b, fc3_w, fc3_b, (float*)d_out);
}

// Round 6
// 8589.538 us; speedup vs baseline: 1.2709x; 1.2709x over previous
//
#include <hip/hip_runtime.h>
#include <math.h>

#define B_   8
#define S_   1024
#define FIN  32
#define D_   512
#define H_   8
#define L_   6
#define DFF_ 2048
#define DK_  64

// non-contracted f32 ops (emulate numpy einsum: separate mul + add, no FMA)
__device__ __forceinline__ float mulrn(float a, float b) { return __fmul_rn(a, b); }
__device__ __forceinline__ float addrn(float a, float b) { return __fadd_rn(a, b); }

// ---------------- embed: h = (x @ emb_w + emb_b) + pe  [f32, sequential-k FMA] ----------------
__global__ __launch_bounds__(128) void k_embed(const float* __restrict__ x,
                                               const float* __restrict__ emb_w,
                                               const float* __restrict__ emb_b,
                                               const float* __restrict__ pe,
                                               float* __restrict__ h) {
    int row = blockIdx.x;            // b*S + s
    int s = row & (S_ - 1);
    int t = threadIdx.x;             // 128 threads, 4 cols each
    __shared__ float xs[FIN];
    if (t < FIN) xs[t] = x[row * FIN + t];
    __syncthreads();
    int d = t * 4;
    float a0 = 0.f, a1 = 0.f, a2 = 0.f, a3 = 0.f;
#pragma unroll
    for (int k = 0; k < FIN; ++k) {          // strict k-ascending single-chain FMA (BLAS-like)
        float xv = xs[k];
        const float* wr = &emb_w[k * D_ + d];
        a0 = fmaf(xv, wr[0], a0);
        a1 = fmaf(xv, wr[1], a1);
        a2 = fmaf(xv, wr[2], a2);
        a3 = fmaf(xv, wr[3], a3);
    }
    const float* bb = &emb_b[d];
    const float* pp = &pe[s * D_ + d];
    float4 o;
    o.x = addrn(addrn(a0, bb[0]), pp[0]);    // (matmul + bias) + pe, np op order
    o.y = addrn(addrn(a1, bb[1]), pp[1]);
    o.z = addrn(addrn(a2, bb[2]), pp[2]);
    o.w = addrn(addrn(a3, bb[3]), pp[3]);
    *(float4*)&h[(size_t)row * D_ + d] = o;
}

// ---------------- tiled f32 GEMM: C = A[M,K] @ W[K,N] + bias ----------------
// Per-element: single accumulator, strict k-ascending FMA chain (matches BLAS sgemm
// micro-kernel semantics). 64x64 tile, BK=16, 256 threads, 4x4 per thread.
template<bool RELU>
__global__ __launch_bounds__(256) void k_gemm(const float* __restrict__ A,
                                              const float* __restrict__ W,
                                              const float* __restrict__ bias,
                                              float* __restrict__ C,
                                              int M, int N, int K) {
    __shared__ float As[16][68];   // [k][m]
    __shared__ float Bs[16][68];   // [k][n]
    int bm = blockIdx.y * 64, bn = blockIdx.x * 64;
    int t = threadIdx.x;
    int tr = t >> 4, tc = t & 15;          // compute map
    int ar = t >> 2, ak = (t & 3) * 4;     // A load map
    int wk = t >> 4, wn = (t & 15) * 4;    // W load map
    float acc[4][4] = {};
    for (int k0 = 0; k0 < K; k0 += 16) {   // k-panels ascending
        float4 a4 = *(const float4*)&A[(size_t)(bm + ar) * K + k0 + ak];
        float4 w4 = *(const float4*)&W[(size_t)(k0 + wk) * N + bn + wn];
        __syncthreads();
        As[ak + 0][ar] = a4.x; As[ak + 1][ar] = a4.y;
        As[ak + 2][ar] = a4.z; As[ak + 3][ar] = a4.w;
        *(float4*)&Bs[wk][wn] = w4;
        __syncthreads();
#pragma unroll
        for (int kk = 0; kk < 16; ++kk) {  // ascending within panel
            float4 av = *(const float4*)&As[kk][tr * 4];
            float4 bv = *(const float4*)&Bs[kk][tc * 4];
            acc[0][0] = fmaf(av.x, bv.x, acc[0][0]); acc[0][1] = fmaf(av.x, bv.y, acc[0][1]);
            acc[0][2] = fmaf(av.x, bv.z, acc[0][2]); acc[0][3] = fmaf(av.x, bv.w, acc[0][3]);
            acc[1][0] = fmaf(av.y, bv.x, acc[1][0]); acc[1][1] = fmaf(av.y, bv.y, acc[1][1]);
            acc[1][2] = fmaf(av.y, bv.z, acc[1][2]); acc[1][3] = fmaf(av.y, bv.w, acc[1][3]);
            acc[2][0] = fmaf(av.z, bv.x, acc[2][0]); acc[2][1] = fmaf(av.z, bv.y, acc[2][1]);
            acc[2][2] = fmaf(av.z, bv.z, acc[2][2]); acc[2][3] = fmaf(av.z, bv.w, acc[2][3]);
            acc[3][0] = fmaf(av.w, bv.x, acc[3][0]); acc[3][1] = fmaf(av.w, bv.y, acc[3][1]);
            acc[3][2] = fmaf(av.w, bv.z, acc[3][2]); acc[3][3] = fmaf(av.w, bv.w, acc[3][3]);
        }
    }
    float4 b4 = *(const float4*)&bias[bn + tc * 4];
#pragma unroll
    for (int i = 0; i < 4; ++i) {
        float4 o;
        o.x = addrn(acc[i][0], b4.x); o.y = addrn(acc[i][1], b4.y);
        o.z = addrn(acc[i][2], b4.z); o.w = addrn(acc[i][3], b4.w);
        if (RELU) {
            o.x = fmaxf(o.x, 0.f); o.y = fmaxf(o.y, 0.f);
            o.z = fmaxf(o.z, 0.f); o.w = fmaxf(o.w, 0.f);
        }
        *(float4*)&C[(size_t)(bm + tr * 4 + i) * N + bn + tc * 4] = o;
    }
}

// ---------------- attention, numpy-faithful f32 (bit-exact rework of round-4) ----------------
// grid (H, S/16, B); block 256 = 16 rows x 16 lanes. Identical arithmetic/order to round-4:
//  scores: strict d-ascending NON-FMA chain, *0.125f;  softmax: per-lane 64-slice max/sum
//  + xor{1,2,4,8} shfl tree;  p/denom via __fdiv_rn;  PV: strict j-ascending NON-FMA chain.
// Changes are layout-only: Q row in registers; K/V staged in KVs[32][68] (float4, ~2-way);
// scores in rotation-swizzled Ss (kills the 16-way stride-64 bank conflicts).
__global__ __launch_bounds__(256) void k_attn(const float* q,
                                              const float* __restrict__ kg,
                                              const float* __restrict__ vg,
                                              float* ctx) {
    __shared__ float KVs[32][68];       // K tiles, then V tiles (time-shared)
    __shared__ float Ss[16 * 1024];     // swizzled scores/attn-weights
    int hh = blockIdx.x;
    int ch = blockIdx.y;
    int b  = blockIdx.z;
    int t  = threadIdx.x;
    int r  = t >> 4, c16 = t & 15;
    const int row0 = ch * 16;
    const size_t base = (size_t)b * S_ * D_ + hh * DK_;

    // swizzled position of score (row r, key j): slice s=j>>6, jj=j&63, rot = s + 8r
    // pos = (r<<10) + (s<<6) + ((jj + s + 8r) & 63)   -- pure layout, values unchanged

    // ---- stage Q chunk via LDS, hoist own row to registers ----
    {
        int rr = t >> 4, cc = (t & 15) * 4;
        *(float4*)&KVs[rr][cc] = *(const float4*)&q[base + (size_t)(row0 + rr) * D_ + cc];
    }
    __syncthreads();
    float4 qr[16];
#pragma unroll
    for (int i = 0; i < 16; ++i) qr[i] = *(float4*)&KVs[r][i * 4];

    // ---- phase A: scores; 32 tiles x 32 keys; each thread keys {c16, c16+16} of tile ----
    for (int kt = 0; kt < 32; ++kt) {
        __syncthreads();   // prior tile reads (or Q reg-copy) done
#pragma unroll
        for (int i = 0; i < 2; ++i) {
            int fid = t + i * 256;             // 512 float4 = 32 rows x 16
            int rr = fid >> 4, cc = (fid & 15) * 4;
            *(float4*)&KVs[rr][cc] = *(const float4*)&kg[base + (size_t)(kt * 32 + rr) * D_ + cc];
        }
        __syncthreads();
        float s0 = 0.f, s1 = 0.f;
#pragma unroll
        for (int d4 = 0; d4 < 16; ++d4) {      // strict d-ascending, no FMA (x,y,z,w order)
            float4 qv = qr[d4];
            float4 k0 = *(float4*)&KVs[c16][d4 * 4];
            float4 k1 = *(float4*)&KVs[c16 + 16][d4 * 4];
            s0 = addrn(s0, mulrn(qv.x, k0.x)); s1 = addrn(s1, mulrn(qv.x, k1.x));
            s0 = addrn(s0, mulrn(qv.y, k0.y)); s1 = addrn(s1, mulrn(qv.y, k1.y));
            s0 = addrn(s0, mulrn(qv.z, k0.z)); s1 = addrn(s1, mulrn(qv.z, k1.z));
            s0 = addrn(s0, mulrn(qv.w, k0.w)); s1 = addrn(s1, mulrn(qv.w, k1.w));
        }
#pragma unroll
        for (int u = 0; u < 2; ++u) {
            int jglob = kt * 32 + u * 16 + c16;
            int sl = jglob >> 6, jj = jglob & 63;
            Ss[(r << 10) + (sl << 6) + ((jj + sl + (r << 3)) & 63)] =
                mulrn(u == 0 ? s0 : s1, 0.125f);          // / sqrt(64), exact as round-4
        }
    }
    __syncthreads();

    // ---- phase B: exact row max (lane's 64-slice j-ascending + xor{1,2,4,8} tree) ----
    const int sbase = (r << 10) + (c16 << 6);
    const int rot   = c16 + (r << 3);
    float mx = -INFINITY;
    for (int j = 0; j < 64; ++j) mx = fmaxf(mx, Ss[sbase + ((j + rot) & 63)]);
    mx = fmaxf(mx, __shfl_xor(mx, 1));
    mx = fmaxf(mx, __shfl_xor(mx, 2));
    mx = fmaxf(mx, __shfl_xor(mx, 4));
    mx = fmaxf(mx, __shfl_xor(mx, 8));

    // ---- phase C: p = exp(s - m); denom; attn = p / denom ----
    float psum = 0.f;
    for (int j = 0; j < 64; ++j) {
        int p_ = sbase + ((j + rot) & 63);
        float p = expf(__fsub_rn(Ss[p_], mx));
        Ss[p_] = p;
        psum = addrn(psum, p);
    }
    psum = addrn(psum, __shfl_xor(psum, 1));
    psum = addrn(psum, __shfl_xor(psum, 2));
    psum = addrn(psum, __shfl_xor(psum, 4));
    psum = addrn(psum, __shfl_xor(psum, 8));
    for (int j = 0; j < 64; ++j) {
        int p_ = sbase + ((j + rot) & 63);
        Ss[p_] = __fdiv_rn(Ss[p_], psum);
    }

    // ---- phase D: ctx[r][d] = sum_j attn[r][j]*v[j][d], strict j-ascending, no FMA ----
    int d0 = c16 * 4;
    float a0 = 0.f, a1 = 0.f, a2 = 0.f, a3 = 0.f;
    for (int vt = 0; vt < 32; ++vt) {
        __syncthreads();   // phase-C writes visible (vt=0) / prior V-tile reads done
#pragma unroll
        for (int i = 0; i < 2; ++i) {
            int fid = t + i * 256;
            int rr = fid >> 4, cc = (fid & 15) * 4;
            *(float4*)&KVs[rr][cc] = *(const float4*)&vg[base + (size_t)(vt * 32 + rr) * D_ + cc];
        }
        __syncthreads();
#pragma unroll 8
        for (int jl = 0; jl < 32; ++jl) {
            int j = vt * 32 + jl;
            int sl = j >> 6;
            float p = Ss[(r << 10) + (sl << 6) + (((j & 63) + sl + (r << 3)) & 63)];
            float4 v4 = *(float4*)&KVs[jl][d0];
            a0 = addrn(a0, mulrn(p, v4.x));
            a1 = addrn(a1, mulrn(p, v4.y));
            a2 = addrn(a2, mulrn(p, v4.z));
            a3 = addrn(a3, mulrn(p, v4.w));
        }
    }
    float4 o = {a0, a1, a2, a3};
    *(float4*)&ctx[base + (size_t)(row0 + r) * D_ + d0] = o;
}

// ---------------- h = LN(h + res), f32 two-pass (np expression order) ----------------
__global__ __launch_bounds__(256) void k_add_ln(float* h,
                                                const float* __restrict__ res,
                                                const float* __restrict__ g,
                                                const float* __restrict__ bta) {
    int row = blockIdx.x;
    int t = threadIdx.x;
    size_t base = (size_t)row * D_;
    float y0 = addrn(h[base + t],       res[base + t]);
    float y1 = addrn(h[base + t + 256], res[base + t + 256]);
    __shared__ float red[4];
    int w = t >> 6;
    float s = y0 + y1;
#pragma unroll
    for (int o = 1; o < 64; o <<= 1) s += __shfl_xor(s, o);
    if ((t & 63) == 0) red[w] = s;
    __syncthreads();
    float mean = (red[0] + red[1] + red[2] + red[3]) * (1.f / D_);
    __syncthreads();
    float d0 = __fsub_rn(y0, mean), d1 = __fsub_rn(y1, mean);
    s = mulrn(d0, d0) + mulrn(d1, d1);
#pragma unroll
    for (int o = 1; o < 64; o <<= 1) s += __shfl_xor(s, o);
    if ((t & 63) == 0) red[w] = s;
    __syncthreads();
    float var = (red[0] + red[1] + red[2] + red[3]) * (1.f / D_);
    float rstd = __fdiv_rn(1.0f, sqrtf(__fadd_rn(var, 1e-5f)));
    h[base + t]       = addrn(mulrn(mulrn(d0, rstd), g[t]),       bta[t]);
    h[base + t + 256] = addrn(mulrn(mulrn(d1, rstd), g[t + 256]), bta[t + 256]);
}

// ---------------- pooled = mean over S (f32) ----------------
__global__ __launch_bounds__(256) void k_pool(const float* __restrict__ h,
                                              float* __restrict__ pooled) {
    int blk = blockIdx.x;           // B*8
    int b = blk >> 3, dc = (blk & 7) * 64;
    int t = threadIdx.x;
    int d = dc + (t & 63), sg = t >> 6;
    float s = 0.f;
    for (int ss = sg; ss < S_; ss += 4)
        s = addrn(s, h[((size_t)b * S_ + ss) * D_ + d]);
    __shared__ float sh[4][64];
    sh[sg][t & 63] = s;
    __syncthreads();
    if (t < 64)
        pooled[b * D_ + dc + t] = (sh[0][t] + sh[1][t] + sh[2][t] + sh[3][t]) * (1.f / S_);
}

// ---------------- head MLP (single block, f32, sequential-k FMA) ----------------
__global__ __launch_bounds__(256) void k_head(const float* __restrict__ pooled,
                                              const float* __restrict__ w1, const float* __restrict__ b1,
                                              const float* __restrict__ w2, const float* __restrict__ b2,
                                              const float* __restrict__ w3, const float* __restrict__ b3,
                                              float* __restrict__ out) {
    __shared__ float ps[B_][D_];
    __shared__ float z1[B_][256];
    __shared__ float z2[B_][128];
    int t = threadIdx.x;
    for (int i = t; i < B_ * D_; i += 256) ps[i >> 9][i & 511] = pooled[i];
    __syncthreads();
    {
        float acc[B_] = {};
        for (int k = 0; k < D_; ++k) {
            float w = w1[k * 256 + t];
#pragma unroll
            for (int b = 0; b < B_; ++b) acc[b] = fmaf(ps[b][k], w, acc[b]);
        }
#pragma unroll
        for (int b = 0; b < B_; ++b) z1[b][t] = fmaxf(addrn(acc[b], b1[t]), 0.f);
    }
    __syncthreads();
    if (t < 128) {
        float acc[B_] = {};
        for (int k = 0; k < 256; ++k) {
            float w = w2[k * 128 + t];
#pragma unroll
            for (int b = 0; b < B_; ++b) acc[b] = fmaf(z1[b][k], w, acc[b]);
        }
#pragma unroll
        for (int b = 0; b < B_; ++b) z2[b][t] = fmaxf(addrn(acc[b], b2[t]), 0.f);
    }
    __syncthreads();
    if (t < B_ * 3) {
        int b = t / 3, c = t % 3;
        float acc = 0.f;
        for (int k = 0; k < 128; ++k) acc = fmaf(z2[b][k], w3[k * 3 + c], acc);
        out[t] = addrn(acc, b3[c]);
    }
}

extern "C" void kernel_launch(void* const* d_in, const int* in_sizes, int n_in,
                              void* d_out, int out_size, void* d_ws, size_t ws_size,
                              hipStream_t stream) {
    const float* x     = (const float*)d_in[0];
    const float* pe    = (const float*)d_in[1];
    const float* emb_w = (const float*)d_in[2];
    const float* emb_b = (const float*)d_in[3];
    const float* Wq    = (const float*)d_in[4];
    const float* bq    = (const float*)d_in[5];
    const float* Wk    = (const float*)d_in[6];
    const float* bk    = (const float*)d_in[7];
    const float* Wv    = (const float*)d_in[8];
    const float* bv    = (const float*)d_in[9];
    const float* Wo    = (const float*)d_in[10];
    const float* bo    = (const float*)d_in[11];
    const float* ln1_g = (const float*)d_in[12];
    const float* ln1_b = (const float*)d_in[13];
    const float* ln2_g = (const float*)d_in[14];
    const float* ln2_b = (const float*)d_in[15];
    const float* W1    = (const float*)d_in[16];
    const float* b1    = (const float*)d_in[17];
    const float* W2    = (const float*)d_in[18];
    const float* b2    = (const float*)d_in[19];
    const float* fc1_w = (const float*)d_in[20];
    const float* fc1_b = (const float*)d_in[21];
    const float* fc2_w = (const float*)d_in[22];
    const float* fc2_b = (const float*)d_in[23];
    const float* fc3_w = (const float*)d_in[24];
    const float* fc3_b = (const float*)d_in[25];

    const size_t NBS = (size_t)B_ * S_ * D_;   // 4,194,304 floats
    float* ws = (float*)d_ws;
    const int MROWS = B_ * S_;                 // 8192

    // layout (f32, 67.1 MB): h | q | k | v | pooled  (ctx->q, Wo-out->k, W2-out->v, ff1 over q+k)
    float* h = ws;
    float* q = h + NBS;
    float* k = q + NBS;
    float* v = k + NBS;
    float* pooled = v + NBS;

    k_embed<<<MROWS, 128, 0, stream>>>(x, emb_w, emb_b, pe, h);

    dim3 g512(D_ / 64, MROWS / 64);        // (8,128)
    dim3 gff(DFF_ / 64, 4096 / 64);        // (32,64)  per 4096-row chunk
    dim3 gw2(D_ / 64, 4096 / 64);          // (8,64)
    dim3 gattn(H_, S_ / 16, B_);           // (8,64,8)

    for (int l = 0; l < L_; ++l) {
        const float* wq = Wq + (size_t)l * D_ * D_;
        const float* wk = Wk + (size_t)l * D_ * D_;
        const float* wv = Wv + (size_t)l * D_ * D_;
        const float* wo = Wo + (size_t)l * D_ * D_;
        k_gemm<false><<<g512, 256, 0, stream>>>(h, wq, bq + l * D_, q, MROWS, D_, D_);
        k_gemm<false><<<g512, 256, 0, stream>>>(h, wk, bk + l * D_, k, MROWS, D_, D_);
        k_gemm<false><<<g512, 256, 0, stream>>>(h, wv, bv + l * D_, v, MROWS, D_, D_);
        k_attn<<<gattn, 256, 0, stream>>>(q, k, v, q);                 // ctx in place
        k_gemm<false><<<g512, 256, 0, stream>>>(q, wo, bo + l * D_, k, MROWS, D_, D_);
        k_add_ln<<<MROWS, 256, 0, stream>>>(h, k, ln1_g + l * D_, ln1_b + l * D_);
        for (int c = 0; c < 2; ++c) {
            float* ff1 = q;                                            // 4096x2048 over dead q+k
            k_gemm<true ><<<gff, 256, 0, stream>>>(h + (size_t)c * 4096 * D_,
                W1 + (size_t)l * D_ * DFF_, b1 + l * DFF_, ff1, 4096, DFF_, D_);
            k_gemm<false><<<gw2, 256, 0, stream>>>(ff1,
                W2 + (size_t)l * DFF_ * D_, b2 + l * D_, v + (size_t)c * 4096 * D_, 4096, D_, DFF_);
        }
        k_add_ln<<<MROWS, 256, 0, stream>>>(h, v, ln2_g + l * D_, ln2_b + l * D_);
    }

    k_pool<<<B_ * 8, 256, 0, stream>>>(h, pooled);
    k_head<<<1, 256, 0, stream>>>(pooled, fc1_w, fc1_b, fc2_w, fc2_b, fc3_w, fc3_b, (float*)d_out);
}